// Round 6
// baseline (2706.990 us; speedup 1.0000x reference)
//
#include <hip/hip_runtime.h>

#define WB 4
#define WN 4096
#define WKNN 20
#define WM 1024
#define WOUTK 8
#define WOD 256
#define BEPS 1e-5f

typedef unsigned long long u64;
typedef unsigned int u32;

// ---- workspace element offsets (floats/ints, 4B units) ----
#define ACC_F    0        // stats [0..1279]; counters at 1280/1281 (memset to 0)
#define CTR_WBAR 1280
#define CTR_FPS  1281
#define IDX1_I   2048     // [B][N][20]
#define IDX2NN_I 329728   // [B][N][20]
#define IDX2_I   657408   // [B][1024]
#define X1_F     661504   // [B][N][64]
#define XX1_F    1710080  // [B][N]
#define X2_F     1726464  // [B][N][64]

// ---- output element offsets ----
#define O_F   0
#define O_C   1048576
#define O_P2A 2097152
#define O_P2B 2109440
#define O_M0  2121728
#define O_M1  2125824

__device__ __forceinline__ u64 shflx64(u64 v, int m){
    int lo = __shfl_xor((int)(u32)(v & 0xFFFFFFFFull), m, 64);
    int hi = __shfl_xor((int)(u32)(v >> 32), m, 64);
    return ((u64)(u32)hi << 32) | (u32)lo;
}
__device__ __forceinline__ u32 encf(float d){
    u32 u = __float_as_uint(d);
    return (u & 0x80000000u) ? ~u : (u | 0x80000000u);
}
template<int L>
__device__ __forceinline__ void ins(u64* lst, u64 key){
    if (key < lst[L-1]){
        #pragma unroll
        for (int j = 0; j < L; ++j){
            u64 a = lst[j];
            u64 mn = key < a ? key : a;
            u64 mx = key < a ? a : key;
            lst[j] = mn; key = mx;
        }
    }
}

// DPP payload-carrying argmax step (HW-verified R3/R4): key = positive finite
// double ((distbits<<32)|tiebreak), f64 compare == u64 compare.
template<int CTRL, int RM>
__device__ __forceinline__ void dppsel(double& k, float& x, float& y, float& z){
    int lo = __double2loint(k), hi = __double2hiint(k);
    int slo = __builtin_amdgcn_update_dpp(lo, lo, CTRL, RM, 0xF, false);
    int shi = __builtin_amdgcn_update_dpp(hi, hi, CTRL, RM, 0xF, false);
    int sx = __builtin_amdgcn_update_dpp(__float_as_int(x), __float_as_int(x), CTRL, RM, 0xF, false);
    int sy = __builtin_amdgcn_update_dpp(__float_as_int(y), __float_as_int(y), CTRL, RM, 0xF, false);
    int sz = __builtin_amdgcn_update_dpp(__float_as_int(z), __float_as_int(z), CTRL, RM, 0xF, false);
    double ok = __hiloint2double(shi, slo);
    bool t = ok > k;
    k = t ? ok : k;
    x = t ? __int_as_float(sx) : x;
    y = t ? __int_as_float(sy) : y;
    z = t ? __int_as_float(sz) : z;
}

struct SmemA { float px[WN], py[WN], pz[WN]; double wk[2][8]; float wx[2][8], wy[2][8], wz[2][8]; };
struct SmemB { float Qt[64*64]; float St[128*68]; float Sxx[128]; };
struct SmemC { float wsm[64*128]; float as[64], aq[64]; };
struct SmemD { float px[WN], py[WN], pz[WN]; float aggs[8][64]; float sacc[1024]; };
union Smem { SmemA a; SmemB b; SmemC c; SmemD d; };

// software global barrier among the 256 worker blocks (monotonic counter)
__device__ __forceinline__ void wbar(u32* ctr, u32 target){
    __syncthreads();
    if (threadIdx.x == 0){
        __threadfence();
        __hip_atomic_fetch_add(ctr, 1u, __ATOMIC_ACQ_REL, __HIP_MEMORY_SCOPE_AGENT);
        long long spins = 0;
        while (__hip_atomic_load(ctr, __ATOMIC_ACQUIRE, __HIP_MEMORY_SCOPE_AGENT) < target){
            __builtin_amdgcn_s_sleep(8);
            if (++spins > (1LL<<22)) break;   // failsafe: no hang
        }
        __threadfence();
    }
    __syncthreads();
}
__device__ __forceinline__ void wait_flag(u32* ctr, u32 target){
    __syncthreads();
    if (threadIdx.x == 0){
        long long spins = 0;
        while (__hip_atomic_load(ctr, __ATOMIC_ACQUIRE, __HIP_MEMORY_SCOPE_AGENT) < target){
            __builtin_amdgcn_s_sleep(8);
            if (++spins > (1LL<<22)) break;
        }
        __threadfence();
    }
    __syncthreads();
}

__global__ __launch_bounds__(512,1)
void mega(const float* __restrict__ x,
          const float* __restrict__ w1, const float* __restrict__ g1, const float* __restrict__ b1,
          const float* __restrict__ w2, const float* __restrict__ g2, const float* __restrict__ b2,
          const float* __restrict__ wf, const float* __restrict__ gf, const float* __restrict__ bf,
          const float* __restrict__ wc, const float* __restrict__ gc, const float* __restrict__ bc,
          float* __restrict__ out, float* __restrict__ wsf, int* __restrict__ wsi)
{
    __shared__ Smem sm;
    float* acc    = wsf + ACC_F;
    int*   idx1   = wsi + IDX1_I;
    int*   idx2nn = wsi + IDX2NN_I;
    int*   idx2   = wsi + IDX2_I;
    float* x1     = wsf + X1_F;
    float* xx1    = wsf + XX1_F;
    float* x2     = wsf + X2_F;
    u32* wctr = (u32*)(wsi + CTR_WBAR);
    u32* fctr = (u32*)(wsi + CTR_FPS);
    int tid = threadIdx.x;

    if (blockIdx.x < 4){
        // ================= FPS (one block per batch, 8 waves x 8 pts/lane) =================
        int b = (int)blockIdx.x;
        const float* xb = x + b*WN*3;
        for (int i = tid; i < WM; i += 512){
            out[O_M0 + b*WM + i] = 1.0f;
            out[O_M1 + b*WM + i] = 1.0f;
        }
        float ptx[8],pty[8],ptz[8],dst[8];
        #pragma unroll
        for (int j=0;j<8;++j){
            int p = tid + j*512;
            ptx[j]=xb[p*3]; pty[j]=xb[p*3+1]; ptz[j]=xb[p*3+2];
            dst[j]=1e10f;
        }
        float lx=xb[0], ly=xb[1], lz=xb[2];
        if (tid==0){
            idx2[b*WM] = 0;
            int o3 = (b*WM)*3;
            out[O_P2A+o3]=lx; out[O_P2A+o3+1]=ly; out[O_P2A+o3+2]=lz;
            out[O_P2B+o3]=lx; out[O_P2B+o3+1]=ly; out[O_P2B+o3+2]=lz;
        }
        int w = tid>>6, lane = tid&63;
        int base = 4095 - tid;
        for (int it=1; it<WM; ++it){
            double bk = -1.0; float bx=lx, by=ly, bz=lz;
            #pragma unroll
            for (int j=0;j<8;++j){
                float dx=ptx[j]-lx, dy=pty[j]-ly, dz=ptz[j]-lz;
                float d = dx*dx + dy*dy + dz*dz;   // keep exact expr (tie-stable, verified)
                d = fminf(dst[j], d); dst[j] = d;
                double kd = __hiloint2double(__float_as_int(d), base - j*512);
                bool t = kd > bk;
                bk = t?kd:bk; bx = t?ptx[j]:bx; by = t?pty[j]:by; bz = t?ptz[j]:bz;
            }
            dppsel<0x111,0xF>(bk,bx,by,bz);   // row_shr:1
            dppsel<0x112,0xF>(bk,bx,by,bz);   // row_shr:2
            dppsel<0x114,0xF>(bk,bx,by,bz);   // row_shr:4
            dppsel<0x118,0xF>(bk,bx,by,bz);   // row_shr:8
            dppsel<0x142,0xA>(bk,bx,by,bz);   // row_bcast:15
            dppsel<0x143,0xC>(bk,bx,by,bz);   // row_bcast:31
            int ib = it & 1;
            if (lane==63){ sm.a.wk[ib][w]=bk; sm.a.wx[ib][w]=bx; sm.a.wy[ib][w]=by; sm.a.wz[ib][w]=bz; }
            __syncthreads();
            int e = lane & 3;
            double k0 = sm.a.wk[ib][e],   k1 = sm.a.wk[ib][e+4];
            float x0 = sm.a.wx[ib][e],   y0 = sm.a.wy[ib][e],   z0 = sm.a.wz[ib][e];
            float x1v= sm.a.wx[ib][e+4], y1v= sm.a.wy[ib][e+4], z1v= sm.a.wz[ib][e+4];
            bool t8 = k1 > k0;
            double gk = t8?k1:k0;
            float gx = t8?x1v:x0, gy = t8?y1v:y0, gz = t8?z1v:z0;
            dppsel<0xB1,0xF>(gk,gx,gy,gz);    // quad_perm xor1
            dppsel<0x4E,0xF>(gk,gx,gy,gz);    // quad_perm xor2
            lx = gx; ly = gy; lz = gz;
            if (tid==0){
                int last = 4095 - (int)(u32)__double2loint(gk);
                idx2[b*WM+it] = last;
                int o3 = (b*WM+it)*3;
                out[O_P2A+o3]=lx; out[O_P2A+o3+1]=ly; out[O_P2A+o3+2]=lz;
                out[O_P2B+o3]=lx; out[O_P2B+o3+1]=ly; out[O_P2B+o3+2]=lz;
            }
        }
        __syncthreads();
        if (tid==0){
            __threadfence();
            __hip_atomic_fetch_add(fctr, 1u, __ATOMIC_RELEASE, __HIP_MEMORY_SCOPE_AGENT);
        }
        return;
    }

    // ===================== worker blocks =====================
    int wb = (int)blockIdx.x - 4;   // 0..255
    int wid = tid>>6, lane = tid&63;

    // ---------- P1: knn1 (64 rows/block, 8 rows/wave) ----------
    {
        int bb = wb >> 6;
        const float* xbk = x + bb*WN*3;
        for (int i = tid; i < WN*3; i += 512){
            float v = xbk[i];
            int n = i/3, c = i - n*3;
            if (c==0) sm.a.px[n]=v; else if (c==1) sm.a.py[n]=v; else sm.a.pz[n]=v;
        }
        __syncthreads();
        for (int rr=0; rr<8; ++rr){
            int n = (wb&63)*64 + wid*8 + rr;
            float qx=sm.a.px[n], qy=sm.a.py[n], qz=sm.a.pz[n];
            float qq = qx*qx+qy*qy+qz*qz;
            u64 lst[WKNN];
            #pragma unroll
            for (int j=0;j<WKNN;++j) lst[j]=~0ull;
            for (int t=0;t<64;++t){
                int c = lane + t*64;
                float sx=sm.a.px[c], sy=sm.a.py[c], sz=sm.a.pz[c];
                float ss = sx*sx+sy*sy+sz*sz;
                float inner = qx*sx+qy*sy+qz*sz;
                float nd = (2.0f*inner - qq) - ss;
                u64 key = ((u64)(0xFFFFFFFFu - encf(nd))<<32) | (u32)c;
                ins<WKNN>(lst, key);
            }
            int ob = (bb*WN + n)*WKNN;
            for (int r=0;r<WKNN;++r){
                u64 k = lst[0];
                #pragma unroll
                for (int m=32;m;m>>=1){ u64 o = shflx64(k,m); k = o<k?o:k; }
                if (lane==0) idx1[ob+r] = (int)(k & 0xFFFFFFFFu);
                if (lst[0]==k){
                    #pragma unroll
                    for (int j=0;j<WKNN-1;++j) lst[j]=lst[j+1];
                    lst[WKNN-1]=~0ull;
                }
            }
        }
    }
    wbar(wctr, 256*1);

    // ---------- P2: ec1 BN stats ----------
    {
        if (tid < 64){ sm.c.as[tid]=0.f; sm.c.aq[tid]=0.f; }
        __syncthreads();
        int cg = tid & 7, sg = tid >> 3, chb = cg*8;
        float w[8][6];
        #pragma unroll
        for (int i=0;i<8;++i){
            #pragma unroll
            for (int j=0;j<6;++j) w[i][j] = w1[(chb+i)*6+j];
        }
        float s[8]={0,0,0,0,0,0,0,0}, q[8]={0,0,0,0,0,0,0,0};
        int s0 = wb*1280 + sg*20;
        for (int i=0;i<20;++i){
            int smp = s0+i;
            int bn = smp/WKNN;
            int j = idx1[smp];
            int bb2 = bn >> 12;
            const float* ct = x + bn*3;
            const float* nb = x + (bb2*WN + j)*3;
            float c0=ct[0],c1=ct[1],c2=ct[2];
            float f0=nb[0]-c0, f1=nb[1]-c1, f2=nb[2]-c2;
            #pragma unroll
            for (int c=0;c<8;++c){
                float y = w[c][0]*f0 + w[c][1]*f1 + w[c][2]*f2
                        + w[c][3]*c0 + w[c][4]*c1 + w[c][5]*c2;
                s[c] += y; q[c] = fmaf(y,y,q[c]);
            }
        }
        #pragma unroll
        for (int c=0;c<8;++c){ atomicAdd(&sm.c.as[chb+c], s[c]); atomicAdd(&sm.c.aq[chb+c], q[c]); }
        __syncthreads();
        if (tid < 64){ atomicAdd(&acc[tid], sm.c.as[tid]); atomicAdd(&acc[64+tid], sm.c.aq[tid]); }
    }
    wbar(wctr, 256*2);

    // ---------- P3: ec1 apply + fused xx1 ----------
    {
        int lin = wb*512 + tid;
        int row = lin >> 3, cg = lin & 7, chb = cg*8;
        int bb2 = row >> 12;
        const float Pinv = 1.0f/(float)(WB*WN*WKNN);
        float aa[8], cc[8], w[8][6];
        #pragma unroll
        for (int i=0;i<8;++i){
            int ch = chb+i;
            float mean = acc[ch]*Pinv;
            float var  = acc[64+ch]*Pinv - mean*mean;
            float rstd = rsqrtf(var + BEPS);
            aa[i] = g1[ch]*rstd;
            cc[i] = b1[ch] - mean*aa[i];
            #pragma unroll
            for (int j=0;j<6;++j) w[i][j]=w1[ch*6+j];
        }
        const float* ct = x + row*3;
        float c0=ct[0],c1=ct[1],c2=ct[2];
        float mx[8];
        #pragma unroll
        for (int i=0;i<8;++i) mx[i] = -1e30f;
        for (int k=0;k<WKNN;++k){
            int j = idx1[row*WKNN+k];
            const float* nb = x + (bb2*WN + j)*3;
            float f0=nb[0]-c0, f1=nb[1]-c1, f2=nb[2]-c2;
            #pragma unroll
            for (int c=0;c<8;++c){
                float y = w[c][0]*f0 + w[c][1]*f1 + w[c][2]*f2
                        + w[c][3]*c0 + w[c][4]*c1 + w[c][5]*c2;
                float v = fmaf(y, aa[c], cc[c]);
                v = fmaxf(v, 0.2f*v);
                mx[c] = fmaxf(mx[c], v);
            }
        }
        float sq2 = 0.f;
        #pragma unroll
        for (int c=0;c<8;++c){ x1[row*64 + chb + c] = mx[c]; sq2 = fmaf(mx[c],mx[c],sq2); }
        sq2 += __shfl_xor(sq2,1,64);
        sq2 += __shfl_xor(sq2,2,64);
        sq2 += __shfl_xor(sq2,4,64);
        if ((tid&7)==0) xx1[row] = sq2;
    }
    wbar(wctr, 256*3);

    // ---------- P4: knn2 (fused GEMM + top-20) ----------
    {
        float* Qt = sm.b.Qt; float* St = sm.b.St; float* Sxx = sm.b.Sxx;
        float* Dt = St;
        int b2 = wb >> 6, qt = wb & 63;
        const float* xbf = x1 + b2*WN*64;
        for (int i=tid; i<64*16; i+=512){
            int r = i>>4, c4 = i&15;
            *(float4*)&Qt[r*64 + c4*4] = *(const float4*)&xbf[(qt*64+r)*64 + c4*4];
        }
        float qxx[8];
        #pragma unroll
        for (int i=0;i<8;++i) qxx[i] = xx1[b2*WN + qt*64 + wid*8 + i];
        u64 lst[WKNN];
        #pragma unroll
        for (int j=0;j<WKNN;++j) lst[j]=~0ull;
        int sq = tid>>3, seg = tid&7;
        for (int ct=0; ct<32; ++ct){
            int cb = ct*128;
            __syncthreads();
            for (int i=tid; i<128*16; i+=512){
                int r=i>>4, c4=i&15;
                *(float4*)&St[r*68 + c4*4] = *(const float4*)&xbf[(cb+r)*64 + c4*4];
            }
            if (tid < 128) Sxx[tid] = xx1[b2*WN + cb + tid];
            __syncthreads();
            float a2[8][2];
            #pragma unroll
            for (int i=0;i<8;++i){ a2[i][0]=0.f; a2[i][1]=0.f; }
            #pragma unroll 4
            for (int d4=0; d4<16; ++d4){
                float4 s0 = *(const float4*)&St[lane*68 + d4*4];
                float4 s1 = *(const float4*)&St[(lane+64)*68 + d4*4];
                #pragma unroll
                for (int i=0;i<8;++i){
                    float4 qv = *(const float4*)&Qt[(wid*8+i)*64 + d4*4];
                    a2[i][0] += qv.x*s0.x + qv.y*s0.y + qv.z*s0.z + qv.w*s0.w;
                    a2[i][1] += qv.x*s1.x + qv.y*s1.y + qv.z*s1.z + qv.w*s1.w;
                }
            }
            __syncthreads();
            float sx0 = Sxx[lane], sx1 = Sxx[lane+64];
            #pragma unroll
            for (int i=0;i<8;++i){
                int r = wid*8+i;
                Dt[r*132 + lane]      = (2.0f*a2[i][0] - qxx[i]) - sx0;
                Dt[r*132 + lane + 64] = (2.0f*a2[i][1] - qxx[i]) - sx1;
            }
            __syncthreads();
            #pragma unroll
            for (int m=0;m<16;++m){
                int col = seg*16+m;
                float nd = Dt[sq*132 + col];
                u64 key = ((u64)(0xFFFFFFFFu - encf(nd))<<32) | (u32)(cb+col);
                ins<WKNN>(lst,key);
            }
        }
        int ob = (b2*WN + qt*64 + sq)*WKNN;
        for (int r=0;r<WKNN;++r){
            u64 k = lst[0];
            #pragma unroll
            for (int m=4;m;m>>=1){ u64 o=shflx64(k,m); k = o<k?o:k; }
            if ((tid&7)==0) idx2nn[ob+r] = (int)(k & 0xFFFFFFFFu);
            if (lst[0]==k){
                #pragma unroll
                for (int j=0;j<WKNN-1;++j) lst[j]=lst[j+1];
                lst[WKNN-1]=~0ull;
            }
        }
    }
    wbar(wctr, 256*4);

    // ---------- P5: ec2 BN stats ----------
    {
        float* wsm = sm.c.wsm;
        for (int i=tid; i<2048; i+=512)
            *(float4*)&wsm[i*4] = *(const float4*)&w2[i*4];
        if (tid<64){ sm.c.as[tid]=0.f; sm.c.aq[tid]=0.f; }
        __syncthreads();
        int row = wb*64 + lane;
        int b2 = row >> 12;
        const float* xr  = x1 + row*64;
        const float* xbb = x1 + b2*WN*64;
        float ss[8]={0,0,0,0,0,0,0,0}, qs[8]={0,0,0,0,0,0,0,0};
        for (int kc=0; kc<5; ++kc){
            int jj[4];
            #pragma unroll
            for (int kk=0;kk<4;++kk) jj[kk] = idx2nn[row*WKNN + kc*4 + kk];
            float av[8][4];
            #pragma unroll
            for (int c=0;c<8;++c){ av[c][0]=0;av[c][1]=0;av[c][2]=0;av[c][3]=0; }
            #pragma unroll 4
            for (int dc=0; dc<16; ++dc){
                float4 cv = *(const float4*)&xr[dc*4];
                float4 fv[4];
                #pragma unroll
                for (int kk=0;kk<4;++kk){
                    float4 nv = *(const float4*)&xbb[jj[kk]*64 + dc*4];
                    fv[kk].x=nv.x-cv.x; fv[kk].y=nv.y-cv.y; fv[kk].z=nv.z-cv.z; fv[kk].w=nv.w-cv.w;
                }
                #pragma unroll
                for (int c=0;c<8;++c){
                    float4 wv = *(const float4*)&wsm[(wid*8+c)*128 + dc*4];
                    #pragma unroll
                    for (int kk=0;kk<4;++kk)
                        av[c][kk] += wv.x*fv[kk].x + wv.y*fv[kk].y + wv.z*fv[kk].z + wv.w*fv[kk].w;
                }
            }
            #pragma unroll 4
            for (int dc=16; dc<32; ++dc){
                float4 cv = *(const float4*)&xr[(dc-16)*4];
                #pragma unroll
                for (int c=0;c<8;++c){
                    float4 wv = *(const float4*)&wsm[(wid*8+c)*128 + dc*4];
                    float dv = wv.x*cv.x + wv.y*cv.y + wv.z*cv.z + wv.w*cv.w;
                    #pragma unroll
                    for (int kk=0;kk<4;++kk) av[c][kk] += dv;
                }
            }
            #pragma unroll
            for (int c=0;c<8;++c){
                #pragma unroll
                for (int kk=0;kk<4;++kk){ ss[c]+=av[c][kk]; qs[c]=fmaf(av[c][kk],av[c][kk],qs[c]); }
            }
        }
        #pragma unroll
        for (int c=0;c<8;++c){ atomicAdd(&sm.c.as[wid*8+c], ss[c]); atomicAdd(&sm.c.aq[wid*8+c], qs[c]); }
        __syncthreads();
        if (tid<64){ atomicAdd(&acc[128+tid], sm.c.as[tid]); atomicAdd(&acc[192+tid], sm.c.aq[tid]); }
    }
    wbar(wctr, 256*5);

    // ---------- P6: ec2 apply ----------
    {
        float* wsm = sm.c.wsm;
        for (int i=tid; i<2048; i+=512)
            *(float4*)&wsm[i*4] = *(const float4*)&w2[i*4];
        __syncthreads();
        const float Pinv = 1.0f/(float)(WB*WN*WKNN);
        float aa[8], cc[8];
        #pragma unroll
        for (int c=0;c<8;++c){
            int ch = wid*8+c;
            float mean = acc[128+ch]*Pinv;
            float var  = acc[192+ch]*Pinv - mean*mean;
            float rstd = rsqrtf(var + BEPS);
            aa[c] = g2[ch]*rstd;
            cc[c] = b2[ch] - mean*aa[c];
        }
        int row = wb*64 + lane;
        int b2 = row>>12;
        const float* xr  = x1 + row*64;
        const float* xbb = x1 + b2*WN*64;
        float mx[8];
        #pragma unroll
        for (int c=0;c<8;++c) mx[c] = -1e30f;
        for (int kc=0;kc<5;++kc){
            int jj[4];
            #pragma unroll
            for (int kk=0;kk<4;++kk) jj[kk]=idx2nn[row*WKNN+kc*4+kk];
            float av[8][4];
            #pragma unroll
            for (int c=0;c<8;++c){ av[c][0]=0;av[c][1]=0;av[c][2]=0;av[c][3]=0; }
            #pragma unroll 4
            for (int dc=0;dc<16;++dc){
                float4 cv = *(const float4*)&xr[dc*4];
                float4 fv[4];
                #pragma unroll
                for (int kk=0;kk<4;++kk){
                    float4 nv = *(const float4*)&xbb[jj[kk]*64 + dc*4];
                    fv[kk].x=nv.x-cv.x; fv[kk].y=nv.y-cv.y; fv[kk].z=nv.z-cv.z; fv[kk].w=nv.w-cv.w;
                }
                #pragma unroll
                for (int c=0;c<8;++c){
                    float4 wv = *(const float4*)&wsm[(wid*8+c)*128 + dc*4];
                    #pragma unroll
                    for (int kk=0;kk<4;++kk)
                        av[c][kk] += wv.x*fv[kk].x + wv.y*fv[kk].y + wv.z*fv[kk].z + wv.w*fv[kk].w;
                }
            }
            #pragma unroll 4
            for (int dc=16;dc<32;++dc){
                float4 cv = *(const float4*)&xr[(dc-16)*4];
                #pragma unroll
                for (int c=0;c<8;++c){
                    float4 wv = *(const float4*)&wsm[(wid*8+c)*128 + dc*4];
                    float dv = wv.x*cv.x + wv.y*cv.y + wv.z*cv.z + wv.w*cv.w;
                    #pragma unroll
                    for (int kk=0;kk<4;++kk) av[c][kk] += dv;
                }
            }
            #pragma unroll
            for (int c=0;c<8;++c){
                #pragma unroll
                for (int kk=0;kk<4;++kk){
                    float v = fmaf(av[c][kk], aa[c], cc[c]);
                    v = fmaxf(v, 0.2f*v);
                    mx[c] = fmaxf(mx[c], v);
                }
            }
        }
        #pragma unroll
        for (int c=0;c<8;++c) x2[row*64 + wid*8 + c] = mx[c];
    }
    wbar(wctr, 256*6);

    // ---------- wait for FPS (one-directional: FPS never stalls) ----------
    wait_flag(fctr, 4u);

    // ---------- P7: out-knn + agg + heads (transposed pre-BN store) ----------
    {
        int b2 = wb >> 6;
        int mb = (wb & 63)*16;
        const float* xb2 = x + b2*WN*3;
        for (int i=tid;i<WN*3;i+=512){
            float v=xb2[i]; int n=i/3,c=i-n*3;
            if(c==0)sm.d.px[n]=v; else if(c==1)sm.d.py[n]=v; else sm.d.pz[n]=v;
        }
        for (int i=tid;i<1024;i+=512) sm.d.sacc[i]=0.f;
        __syncthreads();
        for (int qq=0;qq<2;++qq){
            int m = mb + wid*2 + qq;
            int pi = idx2[b2*WM+m];
            float qx=sm.d.px[pi], qy=sm.d.py[pi], qz=sm.d.pz[pi];
            u64 lst[WOUTK];
            #pragma unroll
            for (int j=0;j<WOUTK;++j) lst[j]=~0ull;
            for (int t=0;t<64;++t){
                int c = lane + t*64;
                float dx=qx-sm.d.px[c], dy=qy-sm.d.py[c], dz=qz-sm.d.pz[c];
                float d = dx*dx+dy*dy+dz*dz;
                u64 key = ((u64)encf(d)<<32) | (u32)c;
                ins<WOUTK>(lst,key);
            }
            int jr[WOUTK];
            #pragma unroll
            for (int r=0;r<WOUTK;++r){
                u64 k=lst[0];
                #pragma unroll
                for (int mm=32;mm;mm>>=1){ u64 o=shflx64(k,mm); k = o<k?o:k; }
                jr[r] = (int)(k&0xFFFFFFFFu);
                if (lst[0]==k){
                    #pragma unroll
                    for (int j=0;j<WOUTK-1;++j) lst[j]=lst[j+1];
                    lst[WOUTK-1]=~0ull;
                }
            }
            float a = 0.f;
            #pragma unroll
            for (int r=0;r<WOUTK;++r) a += x2[(b2*WN + jr[r])*64 + lane];
            a *= 0.125f;
            sm.d.aggs[wid][lane] = a;     // per-wave buffer; same-wave read below
            #pragma unroll
            for (int i2=0;i2<4;++i2){
                int o = lane + 64*i2;
                const float4* wfp = (const float4*)(wf + o*64);
                const float4* wcp = (const float4*)(wc + o*64);
                float af=0.f, ac=0.f;
                #pragma unroll
                for (int d4=0;d4<16;++d4){
                    float4 avv = *(const float4*)&sm.d.aggs[wid][d4*4];
                    float4 w1v = wfp[d4];
                    float4 w2v = wcp[d4];
                    af += w1v.x*avv.x + w1v.y*avv.y + w1v.z*avv.z + w1v.w*avv.w;
                    ac += w2v.x*avv.x + w2v.y*avv.y + w2v.z*avv.z + w2v.w*avv.w;
                }
                out[O_F + (b2*WOD + o)*WM + m] = af;
                out[O_C + (b2*WOD + o)*WM + m] = ac;
                atomicAdd(&sm.d.sacc[o],       af);
                atomicAdd(&sm.d.sacc[256+o],   af*af);
                atomicAdd(&sm.d.sacc[512+o],   ac);
                atomicAdd(&sm.d.sacc[768+o],   ac*ac);
            }
        }
        __syncthreads();
        for (int i=tid;i<1024;i+=512) atomicAdd(&acc[256+i], sm.d.sacc[i]);
    }
    wbar(wctr, 256*7);

    // ---------- P8: in-place BN finalize (coalesced) ----------
    {
        const float Pinv = 1.0f/4096.0f;
        int t0 = wb*8192;
        for (int k=0;k<16;++k){
            int t = t0 + k*512 + tid;
            int half = t >> 20;
            int r = t & 0xFFFFF;
            int o = (r >> 10) & 255;
            float sum = acc[(half?768:256) + o];
            float sq  = acc[(half?1024:512) + o];
            float mean = sum*Pinv;
            float var  = sq*Pinv - mean*mean;
            float rstd = rsqrtf(var + BEPS);
            float g  = half ? gc[o] : gf[o];
            float bb = half ? bc[o] : bf[o];
            float y = out[t];
            out[t] = (y-mean)*rstd*g + bb;
        }
    }
}

extern "C" void kernel_launch(void* const* d_in, const int* in_sizes, int n_in,
                              void* d_out, int out_size, void* d_ws, size_t ws_size,
                              hipStream_t stream){
    const float* x  = (const float*)d_in[0];
    const float* w1 = (const float*)d_in[1];
    const float* g1 = (const float*)d_in[2];
    const float* b1 = (const float*)d_in[3];
    const float* w2 = (const float*)d_in[4];
    const float* g2 = (const float*)d_in[5];
    const float* b2 = (const float*)d_in[6];
    const float* wf = (const float*)d_in[7];
    const float* gf = (const float*)d_in[8];
    const float* bf = (const float*)d_in[9];
    const float* wc = (const float*)d_in[10];
    const float* gc = (const float*)d_in[11];
    const float* bc = (const float*)d_in[12];
    float* out = (float*)d_out;
    float* wsf = (float*)d_ws;
    int*   wsi = (int*)d_ws;

    // zero stats + barrier counters (re-done every launch; graph-capture safe)
    hipMemsetAsync(wsf, 0, 1288*sizeof(float), stream);
    mega<<<260,512,0,stream>>>(x,w1,g1,b1,w2,g2,b2,wf,gf,bf,wc,gc,bc,out,wsf,wsi);
}

// Round 7
// 2493.158 us; speedup vs baseline: 1.0858x; 1.0858x over previous
//
#include <hip/hip_runtime.h>

#define WB 4
#define WN 4096
#define WKNN 20
#define WM 1024
#define WOUTK 8
#define WOD 256
#define BEPS 1e-5f

typedef unsigned long long u64;
typedef unsigned int u32;

// ---- workspace element offsets (floats/ints, 4B units) ----
#define ACC_F    0        // stats [0..1279]; counters at 1280/1281 (memset to 0)
#define CTR_WBAR 1280
#define CTR_FPS  1281
#define IDX1_I   2048     // [B][N][20]
#define IDX2NN_I 329728   // [B][N][20]
#define IDX2_I   657408   // [B][1024]
#define X1_F     661504   // [B][N][64]
#define XX1_F    1710080  // [B][N]
#define X2_F     1726464  // [B][N][64]

// ---- output element offsets ----
#define O_F   0
#define O_C   1048576
#define O_P2A 2097152
#define O_P2B 2109440
#define O_M0  2121728
#define O_M1  2125824

__device__ __forceinline__ u64 shflx64(u64 v, int m){
    int lo = __shfl_xor((int)(u32)(v & 0xFFFFFFFFull), m, 64);
    int hi = __shfl_xor((int)(u32)(v >> 32), m, 64);
    return ((u64)(u32)hi << 32) | (u32)lo;
}
__device__ __forceinline__ u32 encf(float d){
    u32 u = __float_as_uint(d);
    return (u & 0x80000000u) ? ~u : (u | 0x80000000u);
}
template<int L>
__device__ __forceinline__ void ins(u64* lst, u64 key){
    if (key < lst[L-1]){
        #pragma unroll
        for (int j = 0; j < L; ++j){
            u64 a = lst[j];
            u64 mn = key < a ? key : a;
            u64 mx = key < a ? a : key;
            lst[j] = mn; key = mx;
        }
    }
}

// payload select: (ka,pa) = max-by-key of (ka,pa),(kb,pb); key = positive
// finite double ((distbits<<32)|tiebreak) so f64 compare == u64 compare.
__device__ __forceinline__ void sel2(double& ka, float& xa, float& ya, float& za,
                                     double kb, float xb, float yb, float zb){
    bool t = kb > ka;
    ka = t?kb:ka; xa = t?xb:xa; ya = t?yb:ya; za = t?zb:za;
}

// DPP payload-carrying argmax step (HW-verified R3/R4/R6 ctrl constants)
template<int CTRL, int RM>
__device__ __forceinline__ void dppsel(double& k, float& x, float& y, float& z){
    int lo = __double2loint(k), hi = __double2hiint(k);
    int slo = __builtin_amdgcn_update_dpp(lo, lo, CTRL, RM, 0xF, false);
    int shi = __builtin_amdgcn_update_dpp(hi, hi, CTRL, RM, 0xF, false);
    int sx = __builtin_amdgcn_update_dpp(__float_as_int(x), __float_as_int(x), CTRL, RM, 0xF, false);
    int sy = __builtin_amdgcn_update_dpp(__float_as_int(y), __float_as_int(y), CTRL, RM, 0xF, false);
    int sz = __builtin_amdgcn_update_dpp(__float_as_int(z), __float_as_int(z), CTRL, RM, 0xF, false);
    double ok = __hiloint2double(shi, slo);
    bool t = ok > k;
    k = t ? ok : k;
    x = t ? __int_as_float(sx) : x;
    y = t ? __int_as_float(sy) : y;
    z = t ? __int_as_float(sz) : z;
}

struct SmemA { float px[WN], py[WN], pz[WN]; };
struct SmemB { float Qt[64*64]; float St[128*68]; float Sxx[128]; };
struct SmemC { float wsm[64*128]; float as[64], aq[64]; };
struct SmemD { float px[WN], py[WN], pz[WN]; float aggs[8][64]; float sacc[1024]; };
struct SmemF { double wk[2][8]; float wx[2][8], wy[2][8], wz[2][8];
               float bx[WM], by[WM], bz[WM]; int bidx[WM]; };
union Smem { SmemA a; SmemB b; SmemC c; SmemD d; SmemF f; };

// software global barrier among the 256 worker blocks (monotonic counter).
// RELAXED spin polls (no per-poll L2 invalidate) + one trailing fence.
__device__ __forceinline__ void wbar(u32* ctr, u32 target){
    __syncthreads();
    if (threadIdx.x == 0){
        __threadfence();
        __hip_atomic_fetch_add(ctr, 1u, __ATOMIC_RELEASE, __HIP_MEMORY_SCOPE_AGENT);
        long long spins = 0;
        while (__hip_atomic_load(ctr, __ATOMIC_RELAXED, __HIP_MEMORY_SCOPE_AGENT) < target){
            __builtin_amdgcn_s_sleep(32);
            if (++spins > (1LL<<20)) break;   // failsafe: no hang
        }
        __threadfence();
    }
    __syncthreads();
}
__device__ __forceinline__ void wait_flag(u32* ctr, u32 target){
    __syncthreads();
    if (threadIdx.x == 0){
        long long spins = 0;
        while (__hip_atomic_load(ctr, __ATOMIC_RELAXED, __HIP_MEMORY_SCOPE_AGENT) < target){
            __builtin_amdgcn_s_sleep(32);
            if (++spins > (1LL<<20)) break;
        }
        __threadfence();
    }
    __syncthreads();
}

__global__ __launch_bounds__(512,1)
void mega(const float* __restrict__ x,
          const float* __restrict__ w1, const float* __restrict__ g1, const float* __restrict__ b1,
          const float* __restrict__ w2, const float* __restrict__ g2, const float* __restrict__ b2,
          const float* __restrict__ wf, const float* __restrict__ gf, const float* __restrict__ bf,
          const float* __restrict__ wc, const float* __restrict__ gc, const float* __restrict__ bc,
          float* __restrict__ out, float* __restrict__ wsf, int* __restrict__ wsi)
{
    __shared__ Smem sm;
    float* acc    = wsf + ACC_F;
    int*   idx1   = wsi + IDX1_I;
    int*   idx2nn = wsi + IDX2NN_I;
    int*   idx2   = wsi + IDX2_I;
    float* x1     = wsf + X1_F;
    float* xx1    = wsf + XX1_F;
    float* x2     = wsf + X2_F;
    u32* wctr = (u32*)(wsi + CTR_WBAR);
    u32* fctr = (u32*)(wsi + CTR_FPS);
    int tid = threadIdx.x;

    if (blockIdx.x < 4){
        // ========== FPS: 8 waves x 8 pts/lane in regs; NO global stores in
        // the loop (results buffered in LDS -> barrier waits lgkm only);
        // prio 3 so a co-resident worker block cannot starve the chain.
        __builtin_amdgcn_s_setprio(3);
        int b = (int)blockIdx.x;
        const float* xb = x + b*WN*3;
        float ptx[8],pty[8],ptz[8],dst[8];
        #pragma unroll
        for (int j=0;j<8;++j){
            int p = tid + j*512;
            ptx[j]=xb[p*3]; pty[j]=xb[p*3+1]; ptz[j]=xb[p*3+2];
            dst[j]=1e10f;
        }
        float lx=xb[0], ly=xb[1], lz=xb[2];
        if (tid==0){ sm.f.bidx[0]=0; sm.f.bx[0]=lx; sm.f.by[0]=ly; sm.f.bz[0]=lz; }
        int w = tid>>6, lane = tid&63;
        int base = 4095 - tid;
        for (int it=1; it<WM; ++it){
            // dist update + key pack (independent per j)
            double kk[8];
            #pragma unroll
            for (int j=0;j<8;++j){
                float dx=ptx[j]-lx, dy=pty[j]-ly, dz=ptz[j]-lz;
                float d = dx*dx + dy*dy + dz*dz;   // keep exact expr (tie-stable, verified)
                d = fminf(dst[j], d); dst[j] = d;
                kk[j] = __hiloint2double(__float_as_int(d), base - j*512);
            }
            // 3-level payload select tree (ptx/pty/ptz not clobbered)
            double m0=kk[0], m1=kk[2], m2=kk[4], m3=kk[6];
            float ax0=ptx[0],ay0=pty[0],az0=ptz[0];
            float ax1=ptx[2],ay1=pty[2],az1=ptz[2];
            float ax2=ptx[4],ay2=pty[4],az2=ptz[4];
            float ax3=ptx[6],ay3=pty[6],az3=ptz[6];
            sel2(m0,ax0,ay0,az0, kk[1],ptx[1],pty[1],ptz[1]);
            sel2(m1,ax1,ay1,az1, kk[3],ptx[3],pty[3],ptz[3]);
            sel2(m2,ax2,ay2,az2, kk[5],ptx[5],pty[5],ptz[5]);
            sel2(m3,ax3,ay3,az3, kk[7],ptx[7],pty[7],ptz[7]);
            sel2(m0,ax0,ay0,az0, m1,ax1,ay1,az1);
            sel2(m2,ax2,ay2,az2, m3,ax3,ay3,az3);
            sel2(m0,ax0,ay0,az0, m2,ax2,ay2,az2);
            double bk=m0; float bx=ax0, by=ay0, bz=az0;
            // wave payload reduce -> lane 63
            dppsel<0x111,0xF>(bk,bx,by,bz);   // row_shr:1
            dppsel<0x112,0xF>(bk,bx,by,bz);   // row_shr:2
            dppsel<0x114,0xF>(bk,bx,by,bz);   // row_shr:4
            dppsel<0x118,0xF>(bk,bx,by,bz);   // row_shr:8
            dppsel<0x142,0xA>(bk,bx,by,bz);   // row_bcast:15
            dppsel<0x143,0xC>(bk,bx,by,bz);   // row_bcast:31
            int ib = it & 1;
            if (lane==63){ sm.f.wk[ib][w]=bk; sm.f.wx[ib][w]=bx; sm.f.wy[ib][w]=by; sm.f.wz[ib][w]=bz; }
            __syncthreads();
            // cross-wave: 8 entries -> 1 sel + 2-stage quad_perm
            int e = lane & 3;
            double k0 = sm.f.wk[ib][e],   k1 = sm.f.wk[ib][e+4];
            float x0 = sm.f.wx[ib][e],   y0 = sm.f.wy[ib][e],   z0 = sm.f.wz[ib][e];
            float x1v= sm.f.wx[ib][e+4], y1v= sm.f.wy[ib][e+4], z1v= sm.f.wz[ib][e+4];
            bool t8 = k1 > k0;
            double gk = t8?k1:k0;
            float gx = t8?x1v:x0, gy = t8?y1v:y0, gz = t8?z1v:z0;
            dppsel<0xB1,0xF>(gk,gx,gy,gz);    // quad_perm xor1
            dppsel<0x4E,0xF>(gk,gx,gy,gz);    // quad_perm xor2
            lx = gx; ly = gy; lz = gz;
            if (tid==0){
                sm.f.bidx[it] = 4095 - (int)(u32)__double2loint(gk);
                sm.f.bx[it]=lx; sm.f.by[it]=ly; sm.f.bz[it]=lz;
            }
        }
        __syncthreads();
        // cooperative write-out (coalesced, once)
        for (int i=tid;i<WM;i+=512){
            idx2[b*WM+i] = sm.f.bidx[i];
            out[O_M0 + b*WM + i] = 1.0f;
            out[O_M1 + b*WM + i] = 1.0f;
        }
        for (int i=tid;i<WM*3;i+=512){
            int p=i/3, c=i-p*3;
            float v = (c==0)?sm.f.bx[p]:((c==1)?sm.f.by[p]:sm.f.bz[p]);
            out[O_P2A + b*WM*3 + i] = v;
            out[O_P2B + b*WM*3 + i] = v;
        }
        __threadfence();
        __syncthreads();
        if (tid==0)
            __hip_atomic_fetch_add(fctr, 1u, __ATOMIC_RELEASE, __HIP_MEMORY_SCOPE_AGENT);
        return;
    }

    // ===================== worker blocks =====================
    int wb = (int)blockIdx.x - 4;   // 0..255
    int wid = tid>>6, lane = tid&63;

    // ---------- P1: knn1 (64 rows/block, 8 rows/wave) ----------
    {
        int bb = wb >> 6;
        const float* xbk = x + bb*WN*3;
        for (int i = tid; i < WN*3; i += 512){
            float v = xbk[i];
            int n = i/3, c = i - n*3;
            if (c==0) sm.a.px[n]=v; else if (c==1) sm.a.py[n]=v; else sm.a.pz[n]=v;
        }
        __syncthreads();
        for (int rr=0; rr<8; ++rr){
            int n = (wb&63)*64 + wid*8 + rr;
            float qx=sm.a.px[n], qy=sm.a.py[n], qz=sm.a.pz[n];
            float qq = qx*qx+qy*qy+qz*qz;
            u64 lst[WKNN];
            #pragma unroll
            for (int j=0;j<WKNN;++j) lst[j]=~0ull;
            for (int t=0;t<64;++t){
                int c = lane + t*64;
                float sx=sm.a.px[c], sy=sm.a.py[c], sz=sm.a.pz[c];
                float ss = sx*sx+sy*sy+sz*sz;
                float inner = qx*sx+qy*sy+qz*sz;
                float nd = (2.0f*inner - qq) - ss;
                u64 key = ((u64)(0xFFFFFFFFu - encf(nd))<<32) | (u32)c;
                ins<WKNN>(lst, key);
            }
            int ob = (bb*WN + n)*WKNN;
            for (int r=0;r<WKNN;++r){
                u64 k = lst[0];
                #pragma unroll
                for (int m=32;m;m>>=1){ u64 o = shflx64(k,m); k = o<k?o:k; }
                if (lane==0) idx1[ob+r] = (int)(k & 0xFFFFFFFFu);
                if (lst[0]==k){
                    #pragma unroll
                    for (int j=0;j<WKNN-1;++j) lst[j]=lst[j+1];
                    lst[WKNN-1]=~0ull;
                }
            }
        }
    }
    wbar(wctr, 256*1);

    // ---------- P2: ec1 BN stats ----------
    {
        if (tid < 64){ sm.c.as[tid]=0.f; sm.c.aq[tid]=0.f; }
        __syncthreads();
        int cg = tid & 7, sg = tid >> 3, chb = cg*8;
        float w[8][6];
        #pragma unroll
        for (int i=0;i<8;++i){
            #pragma unroll
            for (int j=0;j<6;++j) w[i][j] = w1[(chb+i)*6+j];
        }
        float s[8]={0,0,0,0,0,0,0,0}, q[8]={0,0,0,0,0,0,0,0};
        int s0 = wb*1280 + sg*20;
        for (int i=0;i<20;++i){
            int smp = s0+i;
            int bn = smp/WKNN;
            int j = idx1[smp];
            int bb2 = bn >> 12;
            const float* ct = x + bn*3;
            const float* nb = x + (bb2*WN + j)*3;
            float c0=ct[0],c1=ct[1],c2=ct[2];
            float f0=nb[0]-c0, f1=nb[1]-c1, f2=nb[2]-c2;
            #pragma unroll
            for (int c=0;c<8;++c){
                float y = w[c][0]*f0 + w[c][1]*f1 + w[c][2]*f2
                        + w[c][3]*c0 + w[c][4]*c1 + w[c][5]*c2;
                s[c] += y; q[c] = fmaf(y,y,q[c]);
            }
        }
        #pragma unroll
        for (int c=0;c<8;++c){ atomicAdd(&sm.c.as[chb+c], s[c]); atomicAdd(&sm.c.aq[chb+c], q[c]); }
        __syncthreads();
        if (tid < 64){ atomicAdd(&acc[tid], sm.c.as[tid]); atomicAdd(&acc[64+tid], sm.c.aq[tid]); }
    }
    wbar(wctr, 256*2);

    // ---------- P3: ec1 apply + fused xx1 ----------
    {
        int lin = wb*512 + tid;
        int row = lin >> 3, cg = lin & 7, chb = cg*8;
        int bb2 = row >> 12;
        const float Pinv = 1.0f/(float)(WB*WN*WKNN);
        float aa[8], cc[8], w[8][6];
        #pragma unroll
        for (int i=0;i<8;++i){
            int ch = chb+i;
            float mean = acc[ch]*Pinv;
            float var  = acc[64+ch]*Pinv - mean*mean;
            float rstd = rsqrtf(var + BEPS);
            aa[i] = g1[ch]*rstd;
            cc[i] = b1[ch] - mean*aa[i];
            #pragma unroll
            for (int j=0;j<6;++j) w[i][j]=w1[ch*6+j];
        }
        const float* ct = x + row*3;
        float c0=ct[0],c1=ct[1],c2=ct[2];
        float mx[8];
        #pragma unroll
        for (int i=0;i<8;++i) mx[i] = -1e30f;
        for (int k=0;k<WKNN;++k){
            int j = idx1[row*WKNN+k];
            const float* nb = x + (bb2*WN + j)*3;
            float f0=nb[0]-c0, f1=nb[1]-c1, f2=nb[2]-c2;
            #pragma unroll
            for (int c=0;c<8;++c){
                float y = w[c][0]*f0 + w[c][1]*f1 + w[c][2]*f2
                        + w[c][3]*c0 + w[c][4]*c1 + w[c][5]*c2;
                float v = fmaf(y, aa[c], cc[c]);
                v = fmaxf(v, 0.2f*v);
                mx[c] = fmaxf(mx[c], v);
            }
        }
        float sq2 = 0.f;
        #pragma unroll
        for (int c=0;c<8;++c){ x1[row*64 + chb + c] = mx[c]; sq2 = fmaf(mx[c],mx[c],sq2); }
        sq2 += __shfl_xor(sq2,1,64);
        sq2 += __shfl_xor(sq2,2,64);
        sq2 += __shfl_xor(sq2,4,64);
        if ((tid&7)==0) xx1[row] = sq2;
    }
    wbar(wctr, 256*3);

    // ---------- P4: knn2 (fused GEMM + top-20) ----------
    {
        float* Qt = sm.b.Qt; float* St = sm.b.St; float* Sxx = sm.b.Sxx;
        float* Dt = St;
        int b2 = wb >> 6, qt = wb & 63;
        const float* xbf = x1 + b2*WN*64;
        for (int i=tid; i<64*16; i+=512){
            int r = i>>4, c4 = i&15;
            *(float4*)&Qt[r*64 + c4*4] = *(const float4*)&xbf[(qt*64+r)*64 + c4*4];
        }
        float qxx[8];
        #pragma unroll
        for (int i=0;i<8;++i) qxx[i] = xx1[b2*WN + qt*64 + wid*8 + i];
        u64 lst[WKNN];
        #pragma unroll
        for (int j=0;j<WKNN;++j) lst[j]=~0ull;
        int sq = tid>>3, seg = tid&7;
        for (int ct=0; ct<32; ++ct){
            int cb = ct*128;
            __syncthreads();
            for (int i=tid; i<128*16; i+=512){
                int r=i>>4, c4=i&15;
                *(float4*)&St[r*68 + c4*4] = *(const float4*)&xbf[(cb+r)*64 + c4*4];
            }
            if (tid < 128) Sxx[tid] = xx1[b2*WN + cb + tid];
            __syncthreads();
            float a2[8][2];
            #pragma unroll
            for (int i=0;i<8;++i){ a2[i][0]=0.f; a2[i][1]=0.f; }
            #pragma unroll 4
            for (int d4=0; d4<16; ++d4){
                float4 s0 = *(const float4*)&St[lane*68 + d4*4];
                float4 s1 = *(const float4*)&St[(lane+64)*68 + d4*4];
                #pragma unroll
                for (int i=0;i<8;++i){
                    float4 qv = *(const float4*)&Qt[(wid*8+i)*64 + d4*4];
                    a2[i][0] += qv.x*s0.x + qv.y*s0.y + qv.z*s0.z + qv.w*s0.w;
                    a2[i][1] += qv.x*s1.x + qv.y*s1.y + qv.z*s1.z + qv.w*s1.w;
                }
            }
            __syncthreads();
            float sx0 = Sxx[lane], sx1 = Sxx[lane+64];
            #pragma unroll
            for (int i=0;i<8;++i){
                int r = wid*8+i;
                Dt[r*132 + lane]      = (2.0f*a2[i][0] - qxx[i]) - sx0;
                Dt[r*132 + lane + 64] = (2.0f*a2[i][1] - qxx[i]) - sx1;
            }
            __syncthreads();
            #pragma unroll
            for (int m=0;m<16;++m){
                int col = seg*16+m;
                float nd = Dt[sq*132 + col];
                u64 key = ((u64)(0xFFFFFFFFu - encf(nd))<<32) | (u32)(cb+col);
                ins<WKNN>(lst,key);
            }
        }
        int ob = (b2*WN + qt*64 + sq)*WKNN;
        for (int r=0;r<WKNN;++r){
            u64 k = lst[0];
            #pragma unroll
            for (int m=4;m;m>>=1){ u64 o=shflx64(k,m); k = o<k?o:k; }
            if ((tid&7)==0) idx2nn[ob+r] = (int)(k & 0xFFFFFFFFu);
            if (lst[0]==k){
                #pragma unroll
                for (int j=0;j<WKNN-1;++j) lst[j]=lst[j+1];
                lst[WKNN-1]=~0ull;
            }
        }
    }
    wbar(wctr, 256*4);

    // ---------- P5: ec2 BN stats ----------
    {
        float* wsm = sm.c.wsm;
        for (int i=tid; i<2048; i+=512)
            *(float4*)&wsm[i*4] = *(const float4*)&w2[i*4];
        if (tid<64){ sm.c.as[tid]=0.f; sm.c.aq[tid]=0.f; }
        __syncthreads();
        int row = wb*64 + lane;
        int b2 = row >> 12;
        const float* xr  = x1 + row*64;
        const float* xbb = x1 + b2*WN*64;
        float ss[8]={0,0,0,0,0,0,0,0}, qs[8]={0,0,0,0,0,0,0,0};
        for (int kc=0; kc<5; ++kc){
            int jj[4];
            #pragma unroll
            for (int kk=0;kk<4;++kk) jj[kk] = idx2nn[row*WKNN + kc*4 + kk];
            float av[8][4];
            #pragma unroll
            for (int c=0;c<8;++c){ av[c][0]=0;av[c][1]=0;av[c][2]=0;av[c][3]=0; }
            #pragma unroll 4
            for (int dc=0; dc<16; ++dc){
                float4 cv = *(const float4*)&xr[dc*4];
                float4 fv[4];
                #pragma unroll
                for (int kk=0;kk<4;++kk){
                    float4 nv = *(const float4*)&xbb[jj[kk]*64 + dc*4];
                    fv[kk].x=nv.x-cv.x; fv[kk].y=nv.y-cv.y; fv[kk].z=nv.z-cv.z; fv[kk].w=nv.w-cv.w;
                }
                #pragma unroll
                for (int c=0;c<8;++c){
                    float4 wv = *(const float4*)&wsm[(wid*8+c)*128 + dc*4];
                    #pragma unroll
                    for (int kk=0;kk<4;++kk)
                        av[c][kk] += wv.x*fv[kk].x + wv.y*fv[kk].y + wv.z*fv[kk].z + wv.w*fv[kk].w;
                }
            }
            #pragma unroll 4
            for (int dc=16; dc<32; ++dc){
                float4 cv = *(const float4*)&xr[(dc-16)*4];
                #pragma unroll
                for (int c=0;c<8;++c){
                    float4 wv = *(const float4*)&wsm[(wid*8+c)*128 + dc*4];
                    float dv = wv.x*cv.x + wv.y*cv.y + wv.z*cv.z + wv.w*cv.w;
                    #pragma unroll
                    for (int kk=0;kk<4;++kk) av[c][kk] += dv;
                }
            }
            #pragma unroll
            for (int c=0;c<8;++c){
                #pragma unroll
                for (int kk=0;kk<4;++kk){ ss[c]+=av[c][kk]; qs[c]=fmaf(av[c][kk],av[c][kk],qs[c]); }
            }
        }
        #pragma unroll
        for (int c=0;c<8;++c){ atomicAdd(&sm.c.as[wid*8+c], ss[c]); atomicAdd(&sm.c.aq[wid*8+c], qs[c]); }
        __syncthreads();
        if (tid<64){ atomicAdd(&acc[128+tid], sm.c.as[tid]); atomicAdd(&acc[192+tid], sm.c.aq[tid]); }
    }
    wbar(wctr, 256*5);

    // ---------- P6: ec2 apply ----------
    {
        float* wsm = sm.c.wsm;
        for (int i=tid; i<2048; i+=512)
            *(float4*)&wsm[i*4] = *(const float4*)&w2[i*4];
        __syncthreads();
        const float Pinv = 1.0f/(float)(WB*WN*WKNN);
        float aa[8], cc[8];
        #pragma unroll
        for (int c=0;c<8;++c){
            int ch = wid*8+c;
            float mean = acc[128+ch]*Pinv;
            float var  = acc[192+ch]*Pinv - mean*mean;
            float rstd = rsqrtf(var + BEPS);
            aa[c] = g2[ch]*rstd;
            cc[c] = b2[ch] - mean*aa[c];
        }
        int row = wb*64 + lane;
        int b2 = row>>12;
        const float* xr  = x1 + row*64;
        const float* xbb = x1 + b2*WN*64;
        float mx[8];
        #pragma unroll
        for (int c=0;c<8;++c) mx[c] = -1e30f;
        for (int kc=0;kc<5;++kc){
            int jj[4];
            #pragma unroll
            for (int kk=0;kk<4;++kk) jj[kk]=idx2nn[row*WKNN+kc*4+kk];
            float av[8][4];
            #pragma unroll
            for (int c=0;c<8;++c){ av[c][0]=0;av[c][1]=0;av[c][2]=0;av[c][3]=0; }
            #pragma unroll 4
            for (int dc=0;dc<16;++dc){
                float4 cv = *(const float4*)&xr[dc*4];
                float4 fv[4];
                #pragma unroll
                for (int kk=0;kk<4;++kk){
                    float4 nv = *(const float4*)&xbb[jj[kk]*64 + dc*4];
                    fv[kk].x=nv.x-cv.x; fv[kk].y=nv.y-cv.y; fv[kk].z=nv.z-cv.z; fv[kk].w=nv.w-cv.w;
                }
                #pragma unroll
                for (int c=0;c<8;++c){
                    float4 wv = *(const float4*)&wsm[(wid*8+c)*128 + dc*4];
                    #pragma unroll
                    for (int kk=0;kk<4;++kk)
                        av[c][kk] += wv.x*fv[kk].x + wv.y*fv[kk].y + wv.z*fv[kk].z + wv.w*fv[kk].w;
                }
            }
            #pragma unroll 4
            for (int dc=16;dc<32;++dc){
                float4 cv = *(const float4*)&xr[(dc-16)*4];
                #pragma unroll
                for (int c=0;c<8;++c){
                    float4 wv = *(const float4*)&wsm[(wid*8+c)*128 + dc*4];
                    float dv = wv.x*cv.x + wv.y*cv.y + wv.z*cv.z + wv.w*cv.w;
                    #pragma unroll
                    for (int kk=0;kk<4;++kk) av[c][kk] += dv;
                }
            }
            #pragma unroll
            for (int c=0;c<8;++c){
                #pragma unroll
                for (int kk=0;kk<4;++kk){
                    float v = fmaf(av[c][kk], aa[c], cc[c]);
                    v = fmaxf(v, 0.2f*v);
                    mx[c] = fmaxf(mx[c], v);
                }
            }
        }
        #pragma unroll
        for (int c=0;c<8;++c) x2[row*64 + wid*8 + c] = mx[c];
    }
    wbar(wctr, 256*6);

    // ---------- wait for FPS (should be long done by now) ----------
    wait_flag(fctr, 4u);

    // ---------- P7: out-knn + agg + heads (transposed pre-BN store) ----------
    {
        int b2 = wb >> 6;
        int mb = (wb & 63)*16;
        const float* xb2 = x + b2*WN*3;
        for (int i=tid;i<WN*3;i+=512){
            float v=xb2[i]; int n=i/3,c=i-n*3;
            if(c==0)sm.d.px[n]=v; else if(c==1)sm.d.py[n]=v; else sm.d.pz[n]=v;
        }
        for (int i=tid;i<1024;i+=512) sm.d.sacc[i]=0.f;
        __syncthreads();
        for (int qq=0;qq<2;++qq){
            int m = mb + wid*2 + qq;
            int pi = idx2[b2*WM+m];
            float qx=sm.d.px[pi], qy=sm.d.py[pi], qz=sm.d.pz[pi];
            u64 lst[WOUTK];
            #pragma unroll
            for (int j=0;j<WOUTK;++j) lst[j]=~0ull;
            for (int t=0;t<64;++t){
                int c = lane + t*64;
                float dx=qx-sm.d.px[c], dy=qy-sm.d.py[c], dz=qz-sm.d.pz[c];
                float d = dx*dx+dy*dy+dz*dz;
                u64 key = ((u64)encf(d)<<32) | (u32)c;
                ins<WOUTK>(lst,key);
            }
            int jr[WOUTK];
            #pragma unroll
            for (int r=0;r<WOUTK;++r){
                u64 k=lst[0];
                #pragma unroll
                for (int mm=32;mm;mm>>=1){ u64 o=shflx64(k,mm); k = o<k?o:k; }
                jr[r] = (int)(k&0xFFFFFFFFu);
                if (lst[0]==k){
                    #pragma unroll
                    for (int j=0;j<WOUTK-1;++j) lst[j]=lst[j+1];
                    lst[WOUTK-1]=~0ull;
                }
            }
            float a = 0.f;
            #pragma unroll
            for (int r=0;r<WOUTK;++r) a += x2[(b2*WN + jr[r])*64 + lane];
            a *= 0.125f;
            sm.d.aggs[wid][lane] = a;     // per-wave buffer; same-wave read below
            #pragma unroll
            for (int i2=0;i2<4;++i2){
                int o = lane + 64*i2;
                const float4* wfp = (const float4*)(wf + o*64);
                const float4* wcp = (const float4*)(wc + o*64);
                float af=0.f, ac=0.f;
                #pragma unroll
                for (int d4=0;d4<16;++d4){
                    float4 avv = *(const float4*)&sm.d.aggs[wid][d4*4];
                    float4 w1v = wfp[d4];
                    float4 w2v = wcp[d4];
                    af += w1v.x*avv.x + w1v.y*avv.y + w1v.z*avv.z + w1v.w*avv.w;
                    ac += w2v.x*avv.x + w2v.y*avv.y + w2v.z*avv.z + w2v.w*avv.w;
                }
                out[O_F + (b2*WOD + o)*WM + m] = af;
                out[O_C + (b2*WOD + o)*WM + m] = ac;
                atomicAdd(&sm.d.sacc[o],       af);
                atomicAdd(&sm.d.sacc[256+o],   af*af);
                atomicAdd(&sm.d.sacc[512+o],   ac);
                atomicAdd(&sm.d.sacc[768+o],   ac*ac);
            }
        }
        __syncthreads();
        for (int i=tid;i<1024;i+=512) atomicAdd(&acc[256+i], sm.d.sacc[i]);
    }
    wbar(wctr, 256*7);

    // ---------- P8: in-place BN finalize (coalesced) ----------
    {
        const float Pinv = 1.0f/4096.0f;
        int t0 = wb*8192;
        for (int k=0;k<16;++k){
            int t = t0 + k*512 + tid;
            int half = t >> 20;
            int r = t & 0xFFFFF;
            int o = (r >> 10) & 255;
            float sum = acc[(half?768:256) + o];
            float sq  = acc[(half?1024:512) + o];
            float mean = sum*Pinv;
            float var  = sq*Pinv - mean*mean;
            float rstd = rsqrtf(var + BEPS);
            float g  = half ? gc[o] : gf[o];
            float bb = half ? bc[o] : bf[o];
            float y = out[t];
            out[t] = (y-mean)*rstd*g + bb;
        }
    }
}

extern "C" void kernel_launch(void* const* d_in, const int* in_sizes, int n_in,
                              void* d_out, int out_size, void* d_ws, size_t ws_size,
                              hipStream_t stream){
    const float* x  = (const float*)d_in[0];
    const float* w1 = (const float*)d_in[1];
    const float* g1 = (const float*)d_in[2];
    const float* b1 = (const float*)d_in[3];
    const float* w2 = (const float*)d_in[4];
    const float* g2 = (const float*)d_in[5];
    const float* b2 = (const float*)d_in[6];
    const float* wf = (const float*)d_in[7];
    const float* gf = (const float*)d_in[8];
    const float* bf = (const float*)d_in[9];
    const float* wc = (const float*)d_in[10];
    const float* gc = (const float*)d_in[11];
    const float* bc = (const float*)d_in[12];
    float* out = (float*)d_out;
    float* wsf = (float*)d_ws;
    int*   wsi = (int*)d_ws;

    // zero stats + barrier counters (re-done every launch; graph-capture safe)
    hipMemsetAsync(wsf, 0, 1288*sizeof(float), stream);
    mega<<<260,512,0,stream>>>(x,w1,g1,b1,w2,g2,b2,wf,gf,bf,wc,gc,bc,out,wsf,wsi);
}